// Round 9
// baseline (251.008 us; speedup 1.0000x reference)
//
#include <hip/hip_runtime.h>
#include <hip/hip_bf16.h>

#define N_NODES 100000
#define N_PAD 100096         // 782 * 128
#define N_EDGES 600000
#define CH 128
#define N_GRAPHS 100
#define BN_EPS 1e-5f
#define NBUCKET 32
#define CAP 16               // per-node edge slab = exactly 1 cache line (64B)
#define OVFCAP 8192          // overflow list (deg>16 nodes; ~15 for Poisson(6))
#define FILL_BLOCKS 2344     // ceil(N_EDGES/256), 1 edge/thread
#define PRESCALE_BLOCKS 6250 // N_NODES*16/256
#define WT_BLOCKS 64
#define PHIS_BLOCKS 50       // N_GRAPHS*CH/256
#define GG_BLOCKS 782        // N_PAD/128 (fused gather+gemm)
#define BN_BLOCKS 1563       // ceil(N_NODES/64)

typedef __bf16 bf16x8 __attribute__((ext_vector_type(8)));
typedef float f32x4 __attribute__((ext_vector_type(4)));

__device__ __forceinline__ ushort f2bf(float f) {
    union { float f; unsigned u; } x; x.f = f;
    unsigned u = x.u;
    unsigned r = (u + 0x7fffu + ((u >> 16) & 1u)) >> 16;
    return (ushort)r;
}
__device__ __forceinline__ float bflo(unsigned p) { return __builtin_bit_cast(float, p << 16); }
__device__ __forceinline__ float bfhi(unsigned p) { return __builtin_bit_cast(float, p & 0xffff0000u); }

// ---------------------------------------------------------------------------
// k_front (r1-verified cohabitation): one dispatch, four independent jobs:
//   [0, FILL)      : fused count+fill (slot = atomicAdd(&cnt[dst],1))
//   [..+PRESCALE)  : xh = bf16(h .* norm)   (streaming BW, hides under fill)
//   [..+WT)        : Wt = bf16(W^T)
//   [..+PHIS)      : phis = 0
// cnt/psum/psq/ovfcur zeroed by the preceding hipMemsetAsync.
// ---------------------------------------------------------------------------
__global__ __launch_bounds__(256) void k_front(const int* __restrict__ src,
        const int* __restrict__ dst, const float* __restrict__ h,
        const float* __restrict__ norm, const float* __restrict__ W,
        int* __restrict__ cnt, int* __restrict__ ovfcur, int* __restrict__ ovf,
        int* __restrict__ esrc, ushort* __restrict__ xh, ushort* __restrict__ Wt,
        float* __restrict__ phis) {
    unsigned bid = blockIdx.x;
    int tid = threadIdx.x;
    if (bid < FILL_BLOCKS) {
        int e = bid * 256 + tid;
        if (e < N_EDGES) {
            int d = dst[e], s = src[e];
            int slot = atomicAdd(&cnt[d], 1);
            if (slot < CAP) __builtin_nontemporal_store(s, &esrc[d * CAP + slot]);
            else { int p = atomicAdd(ovfcur, 1); if (p < OVFCAP) { ovf[2*p] = d; ovf[2*p+1] = s; } }
        }
    } else if (bid < FILL_BLOCKS + PRESCALE_BLOCKS) {
        int t = (bid - FILL_BLOCKS) * 256 + tid;   // N_NODES*16
        int n = t >> 4, c = (t & 15) << 3;
        float nm = norm[n];
        float4 a = *(const float4*)(h + (size_t)n * CH + c);
        float4 d = *(const float4*)(h + (size_t)n * CH + c + 4);
        uint4 o;
        o.x = (unsigned)f2bf(a.x * nm) | ((unsigned)f2bf(a.y * nm) << 16);
        o.y = (unsigned)f2bf(a.z * nm) | ((unsigned)f2bf(a.w * nm) << 16);
        o.z = (unsigned)f2bf(d.x * nm) | ((unsigned)f2bf(d.y * nm) << 16);
        o.w = (unsigned)f2bf(d.z * nm) | ((unsigned)f2bf(d.w * nm) << 16);
        *(uint4*)(xh + (size_t)n * CH + c) = o;
    } else if (bid < FILL_BLOCKS + PRESCALE_BLOCKS + WT_BLOCKS) {
        int t = (bid - FILL_BLOCKS - PRESCALE_BLOCKS) * 256 + tid;  // 16384
        int k = t >> 7, o = t & 127;
        Wt[o * CH + k] = f2bf(W[t]);
    } else {
        int i = (bid - FILL_BLOCKS - PRESCALE_BLOCKS - WT_BLOCKS) * 256 + tid;
        phis[i] = 0.f;     // 12800 = 50*256 exactly
    }
}

// ---------------------------------------------------------------------------
// k_gathergemm: row-aligned fusion. Block b owns rows [b*128, b*128+128):
//   phase 1: gather+scale those rows into a 32KB LDS bf16 tile
//            (16B-chunk XOR swizzle: chunk ^= row&7 -> 8 lanes/bank-group)
//   phase 2: r0-verified MFMA GEMM reading A-frags from LDS,
//            epilogue = bias+relu + y16 store + BN bucket stats.
// Deletes the x2 global round-trip (50 MB) and one dispatch boundary.
// ---------------------------------------------------------------------------
__global__ __launch_bounds__(256) void k_gathergemm(const ushort* __restrict__ xh,
        const float* __restrict__ norm, const int* __restrict__ cnt,
        const int* __restrict__ esrc, const int* __restrict__ ovfcur,
        const int* __restrict__ ovf, const float* __restrict__ bias,
        const ushort* __restrict__ Wt, ushort* __restrict__ y16,
        float* __restrict__ psum, float* __restrict__ psq) {
    __shared__ ushort ys[128 * CH];   // 32 KB: A-tile, then result staging

    int tid = threadIdx.x;
    int cg = tid & 15, rl = tid >> 4;
    int c = cg * 8;
    int no = min(*ovfcur, OVFCAP);

    // ---------------- phase 1: gather 128 rows into LDS ----------------
    for (int it = 0; it < 8; it++) {
        int lr = it * 16 + rl;                  // local row 0..127
        int n = blockIdx.x * 128 + lr;
        float a0=0.f,a1=0.f,a2=0.f,a3=0.f,a4=0.f,a5=0.f,a6=0.f,a7=0.f;
        float nn = 0.f;
        if (n < N_NODES) {
            int craw = cnt[n];
            int e = min(craw, CAP);
            nn = norm[n];
            int base = n * CAP;
            int j = 0;
            for (; j + 4 <= e; j += 4) {
                int4 s4 = *(const int4*)(esrc + base + j);
                uint4 v0 = *(const uint4*)(xh + (size_t)s4.x * CH + c);
                uint4 v1 = *(const uint4*)(xh + (size_t)s4.y * CH + c);
                uint4 v2 = *(const uint4*)(xh + (size_t)s4.z * CH + c);
                uint4 v3 = *(const uint4*)(xh + (size_t)s4.w * CH + c);
                a0 += bflo(v0.x) + bflo(v1.x) + bflo(v2.x) + bflo(v3.x);
                a1 += bfhi(v0.x) + bfhi(v1.x) + bfhi(v2.x) + bfhi(v3.x);
                a2 += bflo(v0.y) + bflo(v1.y) + bflo(v2.y) + bflo(v3.y);
                a3 += bfhi(v0.y) + bfhi(v1.y) + bfhi(v2.y) + bfhi(v3.y);
                a4 += bflo(v0.z) + bflo(v1.z) + bflo(v2.z) + bflo(v3.z);
                a5 += bfhi(v0.z) + bfhi(v1.z) + bfhi(v2.z) + bfhi(v3.z);
                a6 += bflo(v0.w) + bflo(v1.w) + bflo(v2.w) + bflo(v3.w);
                a7 += bfhi(v0.w) + bfhi(v1.w) + bfhi(v2.w) + bfhi(v3.w);
            }
            for (; j < e; j++) {
                int s = esrc[base + j];
                uint4 v = *(const uint4*)(xh + (size_t)s * CH + c);
                a0 += bflo(v.x); a1 += bfhi(v.x);
                a2 += bflo(v.y); a3 += bfhi(v.y);
                a4 += bflo(v.z); a5 += bfhi(v.z);
                a6 += bflo(v.w); a7 += bfhi(v.w);
            }
            if (craw > CAP && no > 0) {
                for (int i = 0; i < no; i++) {
                    if (ovf[2*i] == n) {
                        int s = ovf[2*i+1];
                        uint4 v = *(const uint4*)(xh + (size_t)s * CH + c);
                        a0 += bflo(v.x); a1 += bfhi(v.x);
                        a2 += bflo(v.y); a3 += bfhi(v.y);
                        a4 += bflo(v.z); a5 += bfhi(v.z);
                        a6 += bflo(v.w); a7 += bfhi(v.w);
                    }
                }
            }
        }
        uint4 o;
        o.x = (unsigned)f2bf(a0 * nn) | ((unsigned)f2bf(a1 * nn) << 16);
        o.y = (unsigned)f2bf(a2 * nn) | ((unsigned)f2bf(a3 * nn) << 16);
        o.z = (unsigned)f2bf(a4 * nn) | ((unsigned)f2bf(a5 * nn) << 16);
        o.w = (unsigned)f2bf(a6 * nn) | ((unsigned)f2bf(a7 * nn) << 16);
        *(uint4*)(ys + lr * CH + ((cg ^ (lr & 7)) << 3)) = o;   // swizzled
    }
    __syncthreads();

    // ---------------- phase 2: GEMM from LDS ----------------
    int w = tid >> 6, L = tid & 63;
    int c15 = L & 15, quad = L >> 4;
    int sw = c15 & 7;                      // (row&7) for both tiles
    size_t nb = (size_t)blockIdx.x * 128 + w * 32;

    f32x4 acc0[8] = {}, acc1[8] = {};
    #pragma unroll
    for (int kt = 0; kt < 4; kt++) {
        int chsw = ((kt * 4 + quad) ^ sw) << 3;
        bf16x8 a0 = *(const bf16x8*)(ys + (w * 32 + c15) * CH + chsw);
        bf16x8 a1 = *(const bf16x8*)(ys + (w * 32 + 16 + c15) * CH + chsw);
        #pragma unroll
        for (int ot = 0; ot < 8; ot++) {
            bf16x8 b = *(const bf16x8*)(Wt + (size_t)(ot * 16 + c15) * CH + kt * 32 + quad * 8);
            acc0[ot] = __builtin_amdgcn_mfma_f32_16x16x32_bf16(a0, b, acc0[ot], 0, 0, 0);
            acc1[ot] = __builtin_amdgcn_mfma_f32_16x16x32_bf16(a1, b, acc1[ot], 0, 0, 0);
        }
    }
    __syncthreads();   // done reading A-tile; ys is reused below

    float sA[8], qA[8];
    #pragma unroll
    for (int ot = 0; ot < 8; ot++) {
        int col = ot * 16 + c15;
        float bv = bias[col];
        float s_ = 0.f, q_ = 0.f;
        #pragma unroll
        for (int r = 0; r < 4; r++) {
            size_t n = nb + quad * 4 + r;
            float v = fmaxf(acc0[ot][r] + bv, 0.f);
            ys[(w * 32 + quad * 4 + r) * CH + col] = f2bf(v);
            if (n < N_NODES) { s_ += v; q_ += v * v; }
            size_t n2 = n + 16;
            float v2 = fmaxf(acc1[ot][r] + bv, 0.f);
            ys[(w * 32 + 16 + quad * 4 + r) * CH + col] = f2bf(v2);
            if (n2 < N_NODES) { s_ += v2; q_ += v2 * v2; }
        }
        sA[ot] = s_; qA[ot] = q_;
    }
    __syncthreads();

    {   // cooperative coalesced y16 store: 2048 uint4, 8 per thread
        const uint4* ysv = (const uint4*)ys;
        uint4* out = (uint4*)(y16 + (size_t)blockIdx.x * 128 * CH);
        #pragma unroll
        for (int i = 0; i < 8; i++) out[tid + i * 256] = ysv[tid + i * 256];
    }
    __syncthreads();

    float* red = (float*)ys;     // stats reduction (2048 S + 2048 Q)
    #pragma unroll
    for (int ot = 0; ot < 8; ot++) {
        red[ot * 256 + tid] = sA[ot];
        red[2048 + ot * 256 + tid] = qA[ot];
    }
    __syncthreads();

    if (tid < 128) {
        int ot = tid >> 4, cc = tid & 15;
        int col = ot * 16 + cc;
        float S = 0.f, Q = 0.f;
        #pragma unroll
        for (int g = 0; g < 16; g++) {
            int sl = (g >> 2) * 64 + (g & 3) * 16 + cc;
            S += red[ot * 256 + sl];
            Q += red[2048 + ot * 256 + sl];
        }
        int bucket = blockIdx.x & (NBUCKET - 1);
        atomicAdd(&psum[bucket * CH + col], S);
        atomicAdd(&psq[bucket * CH + col], Q);
    }
}

// ---------------------------------------------------------------------------
// k_bnpool: inlined BN finalize (r3-verified; ~8KB L2 broadcast per block) +
// BN apply (bf16 y16 -> f32 x) + per-graph pooling. 64 rows/block.
// ---------------------------------------------------------------------------
__global__ __launch_bounds__(256) void k_bnpool(const ushort* __restrict__ y16,
        const int* __restrict__ gids, const float* __restrict__ psum,
        const float* __restrict__ psq, const float* __restrict__ gamma,
        const float* __restrict__ beta, float* __restrict__ xout,
        float* __restrict__ phis) {
    __shared__ float smP[16][CH];   // 8 KB
    __shared__ float ssc[CH], ssh[CH];

    int tid = threadIdx.x;
    if (tid < 128) {
        float S = 0.f, Q = 0.f;
        #pragma unroll
        for (int g = 0; g < NBUCKET; g++) { S += psum[g * CH + tid]; Q += psq[g * CH + tid]; }
        const float invN = 1.f / (float)N_NODES;
        float mean = S * invN;
        float var  = Q * invN - mean * mean;
        float sc   = gamma[tid] * rsqrtf(var + BN_EPS);
        ssc[tid] = sc;
        ssh[tid] = beta[tid] - mean * sc;
    }
    __syncthreads();

    int cg = tid & 15, rl = tid >> 4;
    int c = cg * 8;
    int r0 = blockIdx.x * 64;
    int rbase = r0 + rl * 4;

    float4 sc0 = *(const float4*)&ssc[c], sc1 = *(const float4*)&ssc[c + 4];
    float4 sh0 = *(const float4*)&ssh[c], sh1 = *(const float4*)&ssh[c + 4];

    bool fast = (r0 + 63 < N_NODES) && (gids[r0] == gids[r0 + 63]);

    if (fast) {
        float4 p0 = make_float4(0.f,0.f,0.f,0.f), p1 = make_float4(0.f,0.f,0.f,0.f);
        #pragma unroll
        for (int j = 0; j < 4; j++) {
            int r = rbase + j;
            uint4 v = *(const uint4*)(y16 + (size_t)r * CH + c);
            float4 f0, f1;
            f0.x = fmaf(bflo(v.x), sc0.x, sh0.x); f0.y = fmaf(bfhi(v.x), sc0.y, sh0.y);
            f0.z = fmaf(bflo(v.y), sc0.z, sh0.z); f0.w = fmaf(bfhi(v.y), sc0.w, sh0.w);
            f1.x = fmaf(bflo(v.z), sc1.x, sh1.x); f1.y = fmaf(bfhi(v.z), sc1.y, sh1.y);
            f1.z = fmaf(bflo(v.w), sc1.z, sh1.z); f1.w = fmaf(bfhi(v.w), sc1.w, sh1.w);
            *(float4*)(xout + (size_t)r * CH + c) = f0;
            *(float4*)(xout + (size_t)r * CH + c + 4) = f1;
            p0.x += f0.x; p0.y += f0.y; p0.z += f0.z; p0.w += f0.w;
            p1.x += f1.x; p1.y += f1.y; p1.z += f1.z; p1.w += f1.w;
        }
        *(float4*)&smP[rl][c] = p0;
        *(float4*)&smP[rl][c + 4] = p1;
        __syncthreads();
        if (tid < 128) {
            int g = gids[r0];
            float S = 0.f;
            #pragma unroll
            for (int k = 0; k < 16; k++) S += smP[k][tid];
            atomicAdd(&phis[(size_t)g * CH + tid], S);
        }
    } else {
        float p[8] = {};
        int gprev = -1;
        #pragma unroll
        for (int j = 0; j < 4; j++) {
            int r = rbase + j;
            if (r >= N_NODES) break;
            int g = gids[r];
            if (g != gprev) {
                if (gprev >= 0) {
                    #pragma unroll
                    for (int k = 0; k < 8; k++) {
                        atomicAdd(&phis[(size_t)gprev * CH + c + k], p[k]);
                        p[k] = 0.f;
                    }
                }
                gprev = g;
            }
            uint4 v = *(const uint4*)(y16 + (size_t)r * CH + c);
            float f[8];
            f[0] = fmaf(bflo(v.x), sc0.x, sh0.x); f[1] = fmaf(bfhi(v.x), sc0.y, sh0.y);
            f[2] = fmaf(bflo(v.y), sc0.z, sh0.z); f[3] = fmaf(bfhi(v.y), sc0.w, sh0.w);
            f[4] = fmaf(bflo(v.z), sc1.x, sh1.x); f[5] = fmaf(bfhi(v.z), sc1.y, sh1.y);
            f[6] = fmaf(bflo(v.w), sc1.z, sh1.z); f[7] = fmaf(bfhi(v.w), sc1.w, sh1.w);
            *(float4*)(xout + (size_t)r * CH + c) = make_float4(f[0], f[1], f[2], f[3]);
            *(float4*)(xout + (size_t)r * CH + c + 4) = make_float4(f[4], f[5], f[6], f[7]);
            #pragma unroll
            for (int k = 0; k < 8; k++) p[k] += f[k];
        }
        if (gprev >= 0) {
            #pragma unroll
            for (int k = 0; k < 8; k++)
                atomicAdd(&phis[(size_t)gprev * CH + c + k], p[k]);
        }
    }
}

// ---------------------------------------------------------------------------
extern "C" void kernel_launch(void* const* d_in, const int* in_sizes, int n_in,
                              void* d_out, int out_size, void* d_ws, size_t ws_size,
                              hipStream_t stream)
{
    const float* h     = (const float*)d_in[0];
    const float* norm  = (const float*)d_in[1];
    const float* W     = (const float*)d_in[2];
    const float* b     = (const float*)d_in[3];
    const float* gamma = (const float*)d_in[4];
    const float* beta  = (const float*)d_in[5];
    const int*   src   = (const int*)d_in[6];
    const int*   dst   = (const int*)d_in[7];
    const int*   gids  = (const int*)d_in[8];

    float* x_out = (float*)d_out;                       // [N,128]
    float* phis  = x_out + (size_t)N_NODES * CH;        // [100,128]

    ushort* xh   = (ushort*)d_ws;                       // [N,128] bf16 h*norm
    ushort* y16  = xh + (size_t)N_NODES * CH;           // [N_PAD,128] bf16 relu(..)
    ushort* Wt   = y16 + (size_t)N_PAD * CH;            // [128,128] bf16 W^T
    // ---- zeroed region (hipMemsetAsync) ----
    int*   cnt     = (int*)(Wt + CH * CH);              // [N]
    float* psum    = (float*)(cnt + N_NODES);           // [32,128]
    float* psq     = psum + NBUCKET * CH;               // [32,128]
    int*   ovfcur  = (int*)(psq + NBUCKET * CH);        // [4]
    // ---- end zeroed region ----
    int*   esrc    = ovfcur + 4;                        // [N*CAP]
    int*   ovf     = esrc + (size_t)N_NODES * CAP;      // [2*OVFCAP]

    hipMemsetAsync(cnt, 0, (size_t)(N_NODES + 2 * NBUCKET * CH + 4) * sizeof(int), stream);

    k_front<<<FILL_BLOCKS + PRESCALE_BLOCKS + WT_BLOCKS + PHIS_BLOCKS, 256, 0, stream>>>(
        src, dst, h, norm, W, cnt, ovfcur, ovf, esrc, xh, Wt, phis);
    k_gathergemm<<<GG_BLOCKS, 256, 0, stream>>>(
        xh, norm, cnt, esrc, ovfcur, ovf, b, Wt, y16, psum, psq);
    k_bnpool<<<BN_BLOCKS, 256, 0, stream>>>(
        y16, gids, psum, psq, gamma, beta, x_out, phis);
}